// Round 6
// baseline (1457.635 us; speedup 1.0000x reference)
//
#include <hip/hip_runtime.h>
#include <hip/hip_bf16.h>
#include <math.h>

#define NLEV 12
#define B_LINES 4096
#define P_PTS 1000
#define FP8_SCALE 65536.0f
#define FP8_ISCALE (1.0f / 65536.0f)
#define NBLK_PER_LEV 256

typedef unsigned short ushort_t;
typedef __attribute__((ext_vector_type(8))) short short8_t;   // 8 bf16 (4 VGPRs)
typedef __attribute__((ext_vector_type(4))) float f32x4;

// Per-level table layout, mirrors _level_specs() exactly.
struct LevelSpec {
    unsigned off;    // entry offset into table (rows of 2 features)
    unsigned mask;   // params-1 (power-of-2 for hash levels)
    float    scale;  // BASE_RES * f^l - 1
    unsigned R;      // res + 1 (dense stride base)
};
struct Specs { LevelSpec L[NLEV]; };
struct HashScales { float s[8]; };   // scales for levels 4..11

static unsigned compute_specs(int D, Specs* sp) {
    double f = pow(8192.0 / 16.0, 1.0 / 11.0);
    unsigned offset = 0;
    for (int l = 0; l < NLEV; ++l) {
        double scale = 16.0 * pow(f, (double)l) - 1.0;
        int res = (int)ceil(scale) + 1;
        unsigned long long dense = 1ull;
        for (int d = 0; d < D; ++d) dense *= (unsigned long long)(res + 1);
        unsigned long long params = dense > (1ull << 21) ? (1ull << 21) : dense;
        params = ((params + 7ull) / 8ull) * 8ull;
        sp->L[l].off   = offset;
        sp->L[l].mask  = (unsigned)params - 1u;
        sp->L[l].scale = (float)scale;
        sp->L[l].R     = (unsigned)(res + 1);
        offset += (unsigned)params;
    }
    return offset;  // total entries
}

// ---------------------------------------------------------------------------

__device__ __forceinline__ float block_reduce_256(float v) {
    __shared__ float red[256];
    int tid = threadIdx.x;
    red[tid] = v;
    __syncthreads();
    #pragma unroll
    for (int s = 128; s >= 1; s >>= 1) {
        if (tid < s) red[tid] += red[tid + s];
        __syncthreads();
    }
    return red[0];
}

__device__ __forceinline__ unsigned short f32_to_bf16_bits(float f) {
    unsigned u = __float_as_uint(f);
    unsigned r = (u + 0x7fffu + ((u >> 16) & 1u)) >> 16;   // RNE
    return (unsigned short)r;
}

// bf16x2 pack of one level's (a0,a1) feature pair (same bits the old dense
// kernel stored to featbuf -> numerically identical pipeline).
__device__ __forceinline__ unsigned pack_feat(float a0, float a1) {
    union { __hip_bfloat162 b; unsigned u; } cv;
    cv.b.x = __float2bfloat16(a0 * FP8_ISCALE);
    cv.b.y = __float2bfloat16(a1 * FP8_ISCALE);
    return cv.u;
}

__device__ __forceinline__ void store_nt_u32(unsigned v, unsigned* p) {
    __builtin_nontemporal_store(v, p);
}

// Aligned-pair table read: one u32 covers entries {H&~1, (H&~1)+1}; select
// the 2-byte entry by H&1. Even-g0 x-corner pairs share the same u32/line.
__device__ __forceinline__ int pair_entry(const ushort_t* __restrict__ base,
                                          unsigned H) {
    unsigned w = *(const unsigned*)(base + (H & ~1u));
    return (int)((w >> ((H & 1u) << 4)) & 0xffffu);
}

// MLP 24 -> 64(relu) -> 1; weights wave-uniform -> s_load + v_fmac.
// (used by the fallback mono path and conf path)
__device__ __forceinline__ float mlp_24_64_1(const float feat[24],
        const float* __restrict__ w1, const float* __restrict__ b1,
        const float* __restrict__ w2, const float* __restrict__ b2) {
    float o = b2[0];
    #pragma unroll
    for (int half = 0; half < 2; ++half) {
        float h[32];
        #pragma unroll
        for (int j = 0; j < 32; ++j) h[j] = b1[half * 32 + j];
        #pragma unroll
        for (int k = 0; k < 24; ++k) {
            float fv = feat[k];
            #pragma unroll
            for (int j = 0; j < 32; ++j)
                h[j] = fmaf(fv, w1[k * 64 + half * 32 + j], h[j]);
        }
        #pragma unroll
        for (int j = 0; j < 32; ++j)
            o = fmaf(fmaxf(h[j], 0.f), w2[half * 32 + j], o);
    }
    return o;
}

// ---------------------------------------------------------------------------
// fp8 table conversion: one row (2 features) -> 2 bytes, scaled by 2^16.
__global__ void __launch_bounds__(256) convert_kernel(
        const float2* __restrict__ in, ushort_t* __restrict__ out, int n) {
    int i = blockIdx.x * 256 + threadIdx.x;
    if (i >= n) return;
    float2 v;
    v.x = __builtin_nontemporal_load(&in[i].x);
    v.y = __builtin_nontemporal_load(&in[i].y);
    int p = __builtin_amdgcn_cvt_pk_fp8_f32(v.x * FP8_SCALE, v.y * FP8_SCALE,
                                            0, false);
    __builtin_nontemporal_store((ushort_t)(p & 0xffff), &out[i]);
}

// Per-point hash addresses + fractional weights (cached pts loads: pts sit
// in L2/L3 after the first level pass).
struct HashPt { unsigned h[8]; float r0, r1, r2; };

__device__ __forceinline__ HashPt hash_addrs(
        const float* __restrict__ pts, int gp, float scale, unsigned m) {
    float x0 = (pts[3 * gp + 0] + 1.f) * 0.5f;
    float x1 = (pts[3 * gp + 1] + 1.f) * 0.5f;
    float x2 = (pts[3 * gp + 2] + 1.f) * 0.5f;
    float p0 = x0 * scale + 0.5f;
    float p1 = x1 * scale + 0.5f;
    float p2 = x2 * scale + 0.5f;
    float f0 = floorf(p0), f1 = floorf(p1), f2 = floorf(p2);
    HashPt o;
    o.r0 = p0 - f0; o.r1 = p1 - f1; o.r2 = p2 - f2;
    unsigned g0 = (unsigned)f0, g1 = (unsigned)f1, g2 = (unsigned)f2;
    unsigned y0 = g1 * 2654435761u, y1 = y0 + 2654435761u;
    unsigned z0 = g2 * 805459861u,  z1 = z0 + 805459861u;
    #pragma unroll
    for (int c = 0; c < 8; ++c) {
        unsigned h = (g0 + ((c & 1) ? 1u : 0u))
                   ^ ((c & 2) ? y1 : y0) ^ ((c & 4) ? z1 : z0);
        o.h[c] = h & m;
    }
    return o;
}

__device__ __forceinline__ void interp_store(
        const int t[8], const HashPt& hp, unsigned* dst) {
    float u0 = 1.f - hp.r0, u1 = 1.f - hp.r1, u2 = 1.f - hp.r2;
    float a0 = 0.f, a1 = 0.f;
    #pragma unroll
    for (int c = 0; c < 8; ++c) {
        float w = ((c & 1) ? hp.r0 : u0) * ((c & 2) ? hp.r1 : u1)
                * ((c & 4) ? hp.r2 : u2);
        a0 = fmaf(w, __builtin_amdgcn_cvt_f32_fp8(t[c], 0), a0);
        a1 = fmaf(w, __builtin_amdgcn_cvt_f32_fp8(t[c], 1), a1);
    }
    store_nt_u32(pack_feat(a0, a1), dst);
}

// All 8 hash levels in ONE persistent launch, XCD-pinned: level = blockIdx&7,
// so with round-robin block->XCD dispatch each XCD's 4 MB L2 holds exactly
// ONE level's 4 MB fp8 table for the whole kernel. 4 pts/thread. Feat slabs
// are now 8 (dense levels moved into the MLP kernel).
__global__ void __launch_bounds__(256) enc_hash_all_kernel(
        const float* __restrict__ pts, int pbase, int npts,
        const ushort_t* __restrict__ tabq, unsigned hash_off0,
        HashScales hs,
        unsigned* __restrict__ feats) {          // 8 slabs of npts (u32)
    const int lev = blockIdx.x & 7;              // 0..7 -> level 4+lev
    const int bpl = blockIdx.x >> 3;             // block index within level
    const int tid = threadIdx.x;
    float scale = hs.s[0];
    #pragma unroll
    for (int k = 1; k < 8; ++k) if (lev == k) scale = hs.s[k];  // cselect x7
    const ushort_t* __restrict__ base =
        tabq + hash_off0 + ((unsigned)lev << 21);
    const unsigned m = (1u << 21) - 1u;
    unsigned* __restrict__ slab = feats + (size_t)lev * npts;

    const int stride = NBLK_PER_LEV * 1024;
    for (int p0 = bpl * 1024; p0 < npts; p0 += stride) {
        int  idx[4];
        bool val[4];
        HashPt hp[4];
        int  t[4][8];
        #pragma unroll
        for (int q = 0; q < 4; ++q) {
            int i = p0 + q * 256 + tid;
            val[q] = i < npts;
            idx[q] = val[q] ? i : npts - 1;
            hp[q]  = hash_addrs(pts, pbase + idx[q], scale, m);
            #pragma unroll
            for (int c = 0; c < 8; ++c)
                t[q][c] = pair_entry(base, hp[q].h[c]);
        }
        #pragma unroll
        for (int q = 0; q < 4; ++q)
            if (val[q]) interp_store(t[q], hp[q], slab + idx[q]);
    }
}

// ---------------------------------------------------------------------------
// Fused dense-encode + MFMA MLP + weighted |op-gt| sum. One block per line.
// Phase 1: all 256 threads compute dense levels 0..3 for the block's 1000
//   points into LDS (16 KB; small dense tables are L2-resident everywhere).
// Phase 2: 16x16x32 bf16 MFMA MLP; k-group g==0 sources its A-fragment from
//   LDS, g==1/2 from the 8 hash slabs (nt loads: no reuse), g==3 zeros.
// Layouts (gfx950 16x16x32 bf16):
//   A: lane l holds A[l&15][(l>>4)*8 + i]           (i = 0..7)
//   B: lane l holds B[(l>>4)*8 + i][l&15]
//   D: lane l holds D[(l>>4)*4 + r][l&15]           (r = 0..3)
__global__ void __launch_bounds__(256) mlp_loss_fused_kernel(
        const float* __restrict__ pts,
        const unsigned* __restrict__ hfeats, int npts,
        const float* __restrict__ gt, int line0,
        const ushort_t* __restrict__ tabq,
        const float* __restrict__ w1, const float* __restrict__ b1,
        const float* __restrict__ w2, const float* __restrict__ b2,
        float* __restrict__ S, Specs sp) {
    __shared__ unsigned ldsd[4 * P_PTS];   // [level][point] bf16x2
    const int line_local = blockIdx.x;
    const int line = line0 + line_local;
    const int tid  = threadIdx.x;

    // ---- phase 1: dense levels 0..3 -> LDS (identical math to old kernel)
    for (int p = tid; p < P_PTS; p += 256) {
        int gp = line * P_PTS + p;
        float x0 = (pts[3 * gp + 0] + 1.f) * 0.5f;
        float x1 = (pts[3 * gp + 1] + 1.f) * 0.5f;
        float x2 = (pts[3 * gp + 2] + 1.f) * 0.5f;
        #pragma unroll
        for (int l = 0; l < 4; ++l) {
            const LevelSpec L = sp.L[l];
            float p0 = x0 * L.scale + 0.5f;
            float p1 = x1 * L.scale + 0.5f;
            float p2 = x2 * L.scale + 0.5f;
            float f0 = floorf(p0), f1 = floorf(p1), f2 = floorf(p2);
            float r0 = p0 - f0, r1 = p1 - f1, r2 = p2 - f2;
            float u0 = 1.f - r0, u1 = 1.f - r1, u2 = 1.f - r2;
            unsigned g0 = (unsigned)f0, g1 = (unsigned)f1, g2 = (unsigned)f2;
            const ushort_t* __restrict__ base = tabq + L.off;
            unsigned R = L.R, R2 = R * R;
            unsigned y0 = g1 * R, y1 = y0 + R;
            unsigned z0 = g2 * R2, z1 = z0 + R2;
            int t[8];
            #pragma unroll
            for (int cz = 0; cz < 4; ++cz) {
                unsigned i0 = g0 + ((cz & 1) ? y1 : y0) + ((cz & 2) ? z1 : z0);
                t[2 * cz]     = pair_entry(base, i0);
                t[2 * cz + 1] = pair_entry(base, i0 + 1u);
            }
            float a0 = 0.f, a1 = 0.f;
            #pragma unroll
            for (int c = 0; c < 8; ++c) {
                float w = ((c & 1) ? r0 : u0) * ((c & 2) ? r1 : u1)
                        * ((c & 4) ? r2 : u2);
                a0 = fmaf(w, __builtin_amdgcn_cvt_f32_fp8(t[c], 0), a0);
                a1 = fmaf(w, __builtin_amdgcn_cvt_f32_fp8(t[c], 1), a1);
            }
            ldsd[l * P_PTS + p] = pack_feat(a0, a1);
        }
    }
    __syncthreads();

    // ---- phase 2: MFMA MLP
    const int wave = tid >> 6;
    const int lane = tid & 63;
    const int c = lane & 15;      // hidden col within 16 / A point row
    const int g = lane >> 4;      // k-group (0..3)

    short8_t bfrag[4];
    #pragma unroll
    for (int nb = 0; nb < 4; ++nb) {
        #pragma unroll
        for (int i = 0; i < 8; ++i) {
            int k = g * 8 + i;
            float v = (k < 24) ? w1[k * 64 + nb * 16 + c] : 0.f;
            bfrag[nb][i] = (short)f32_to_bf16_bits(v);
        }
    }
    float b1v[4], w2v[4];
    #pragma unroll
    for (int nb = 0; nb < 4; ++nb) {
        b1v[nb] = b1[nb * 16 + c];
        w2v[nb] = w2[nb * 16 + c];
    }
    const float b2v = b2[0];

    const size_t lbase = (size_t)line_local * P_PTS;
    float lsum = 0.f;

    for (int it = 0; it < 16; ++it) {
        const int base16 = it * 64 + wave * 16;
        int prow = base16 + c;
        int pcl  = prow < P_PTS ? prow : P_PTS - 1;
        size_t pidx = lbase + (size_t)pcl;
        union { unsigned u[4]; short8_t v; } a;
        if (g == 0) {                 // dense levels 0..3 from LDS
            #pragma unroll
            for (int s = 0; s < 4; ++s)
                a.u[s] = ldsd[s * P_PTS + pcl];
        } else if (g < 3) {           // hash slabs (levels 4..11), nt
            #pragma unroll
            for (int s = 0; s < 4; ++s)
                a.u[s] = __builtin_nontemporal_load(
                    &hfeats[(size_t)((g - 1) * 4 + s) * npts + pidx]);
        } else {
            a.u[0] = 0u; a.u[1] = 0u; a.u[2] = 0u; a.u[3] = 0u;
        }
        f32x4 acc[4];
        #pragma unroll
        for (int nb = 0; nb < 4; ++nb) {
            f32x4 ci = {b1v[nb], b1v[nb], b1v[nb], b1v[nb]};
            acc[nb] = __builtin_amdgcn_mfma_f32_16x16x32_bf16(
                a.v, bfrag[nb], ci, 0, 0, 0);
        }
        float part[4];
        #pragma unroll
        for (int r = 0; r < 4; ++r) {
            float s = fmaxf(acc[0][r], 0.f) * w2v[0];
            s = fmaf(fmaxf(acc[1][r], 0.f), w2v[1], s);
            s = fmaf(fmaxf(acc[2][r], 0.f), w2v[2], s);
            s = fmaf(fmaxf(acc[3][r], 0.f), w2v[3], s);
            part[r] = s;
        }
        #pragma unroll
        for (int off = 1; off < 16; off <<= 1) {
            #pragma unroll
            for (int r = 0; r < 4; ++r)
                part[r] += __shfl_xor(part[r], off);
        }
        if (c < 4) {
            int p = base16 + g * 4 + c;
            if (p < P_PTS) {
                float op = part[c] + b2v;
                float gv = __builtin_nontemporal_load(
                    &gt[(size_t)line * P_PTS + p]);
                float cw = (p < 500) ? (float)(4.0 / 3.0) : (float)(2.0 / 3.0);
                lsum += fabsf(op - gv) * cw;
            }
        }
    }
    float tot = block_reduce_256(lsum);
    if (tid == 0) S[line] = tot;
}

// ---------------------------------------------------------------------------
// Fallback monolithic opacity kernel (R1 structure) if ws is too small.
__global__ void __launch_bounds__(256) opacity_mono_kernel(
        const float* __restrict__ pts, const float* __restrict__ gt,
        const float2* __restrict__ tab,
        const float* __restrict__ w1, const float* __restrict__ b1,
        const float* __restrict__ w2, const float* __restrict__ b2,
        float* __restrict__ S, Specs sp) {
    const int b = blockIdx.x;
    const int tid = threadIdx.x;
    float lsum = 0.f;
    for (int p = tid; p < P_PTS; p += 256) {
        const int i = b * P_PTS + p;
        float x0 = (pts[3 * i + 0] + 1.f) * 0.5f;
        float x1 = (pts[3 * i + 1] + 1.f) * 0.5f;
        float x2 = (pts[3 * i + 2] + 1.f) * 0.5f;
        float feat[24];
        #pragma unroll
        for (int l = 0; l < NLEV; ++l) {
            const LevelSpec L = sp.L[l];
            float p0 = x0 * L.scale + 0.5f;
            float p1 = x1 * L.scale + 0.5f;
            float p2 = x2 * L.scale + 0.5f;
            float f0 = floorf(p0), f1 = floorf(p1), f2 = floorf(p2);
            float r0 = p0 - f0, r1 = p1 - f1, r2 = p2 - f2;
            float u0 = 1.f - r0, u1 = 1.f - r1, u2 = 1.f - r2;
            unsigned g0 = (unsigned)f0, g1 = (unsigned)f1, g2 = (unsigned)f2;
            float a0 = 0.f, a1 = 0.f;
            if (l >= 4) {
                unsigned y0 = g1 * 2654435761u, y1 = y0 + 2654435761u;
                unsigned z0 = g2 * 805459861u,  z1 = z0 + 805459861u;
                unsigned m = L.mask;
                #pragma unroll
                for (int c = 0; c < 8; ++c) {
                    unsigned h = (g0 + ((c & 1) ? 1u : 0u))
                               ^ ((c & 2) ? y1 : y0) ^ ((c & 4) ? z1 : z0);
                    float2 t = tab[L.off + (h & m)];
                    float w = ((c & 1) ? r0 : u0) * ((c & 2) ? r1 : u1)
                            * ((c & 4) ? r2 : u2);
                    a0 = fmaf(w, t.x, a0); a1 = fmaf(w, t.y, a1);
                }
            } else {
                unsigned R = L.R, R2 = R * R;
                unsigned y0 = g1 * R, y1 = y0 + R;
                unsigned z0 = g2 * R2, z1 = z0 + R2;
                #pragma unroll
                for (int c = 0; c < 8; ++c) {
                    unsigned idx = (g0 + ((c & 1) ? 1u : 0u))
                                 + ((c & 2) ? y1 : y0) + ((c & 4) ? z1 : z0);
                    float2 t = tab[L.off + idx];
                    float w = ((c & 1) ? r0 : u0) * ((c & 2) ? r1 : u1)
                            * ((c & 4) ? r2 : u2);
                    a0 = fmaf(w, t.x, a0); a1 = fmaf(w, t.y, a1);
                }
            }
            feat[2 * l] = a0; feat[2 * l + 1] = a1;
        }
        float op = mlp_24_64_1(feat, w1, b1, w2, b2);
        float cw = (p < 500) ? (float)(4.0 / 3.0) : (float)(2.0 / 3.0);
        lsum += fabsf(op - gt[i]) * cw;
    }
    float tot = block_reduce_256(lsum);
    if (tid == 0) S[b] = tot;
}

// Confidence (D=2, tiny) + final reduction: unchanged (f32 table).
__global__ void __launch_bounds__(256) conf_kernel(
        const float* __restrict__ line, const float2* __restrict__ tab,
        const float* __restrict__ w1, const float* __restrict__ b1,
        const float* __restrict__ w2, const float* __restrict__ b2,
        const float* __restrict__ S, float* __restrict__ partial, Specs sp) {
    const int b = blockIdx.x * 256 + threadIdx.x;
    float x0 = (line[2 * b + 0] + 1.f) * 0.5f;
    float x1 = (line[2 * b + 1] + 1.f) * 0.5f;
    float feat[24];
    #pragma unroll
    for (int l = 0; l < NLEV; ++l) {
        const unsigned off = sp.L[l].off;
        const float scale = sp.L[l].scale;
        float p0 = x0 * scale + 0.5f;
        float p1 = x1 * scale + 0.5f;
        float f0 = floorf(p0), f1 = floorf(p1);
        float r0 = p0 - f0, r1 = p1 - f1;
        float u0 = 1.f - r0, u1 = 1.f - r1;
        unsigned g0 = (unsigned)f0, g1 = (unsigned)f1;
        unsigned idx0, idx1, idx2, idx3;
        if (l >= 8) {
            const unsigned mask = sp.L[l].mask;
            unsigned a1 = g1 * 2654435761u, bb1 = a1 + 2654435761u;
            idx0 = (g0 ^ a1) & mask;
            idx1 = ((g0 + 1u) ^ a1) & mask;
            idx2 = (g0 ^ bb1) & mask;
            idx3 = ((g0 + 1u) ^ bb1) & mask;
        } else {
            const unsigned R = sp.L[l].R;
            unsigned a1 = g1 * R, bb1 = a1 + R;
            idx0 = g0 + a1; idx1 = g0 + 1u + a1;
            idx2 = g0 + bb1; idx3 = g0 + 1u + bb1;
        }
        float2 t0 = tab[off + idx0], t1 = tab[off + idx1];
        float2 t2 = tab[off + idx2], t3 = tab[off + idx3];
        float w0 = u0 * u1, w1c = r0 * u1, w2c = u0 * r1, w3 = r0 * r1;
        feat[2 * l]     = w0 * t0.x + w1c * t1.x + w2c * t2.x + w3 * t3.x;
        feat[2 * l + 1] = w0 * t0.y + w1c * t1.y + w2c * t2.y + w3 * t3.y;
    }
    float conf = mlp_24_64_1(feat, w1, b1, w2, b2);
    float term = expf(-conf) * (S[b] * (1.0f / (float)P_PTS)) + conf;
    float tot = block_reduce_256(term);
    if (threadIdx.x == 0) partial[blockIdx.x] = tot;
}

__global__ void final_kernel(const float* __restrict__ partial,
                             float* __restrict__ out) {
    if (threadIdx.x == 0) {
        float s = 0.f;
        for (int i = 0; i < 16; ++i) s += partial[i];
        out[0] = s * (1.0f / (float)B_LINES);
    }
}

// ---------------------------------------------------------------------------

extern "C" void kernel_launch(void* const* d_in, const int* in_sizes, int n_in,
                              void* d_out, int out_size, void* d_ws, size_t ws_size,
                              hipStream_t stream) {
    const float* line    = (const float*)d_in[0];
    const float* pts     = (const float*)d_in[1];
    const float* gt      = (const float*)d_in[2];
    const float* table_c = (const float*)d_in[3];
    const float* w1_c    = (const float*)d_in[4];
    const float* b1_c    = (const float*)d_in[5];
    const float* w2_c    = (const float*)d_in[6];
    const float* b2_c    = (const float*)d_in[7];
    const float* table_o = (const float*)d_in[8];
    const float* w1_o    = (const float*)d_in[9];
    const float* b1_o    = (const float*)d_in[10];
    const float* w2_o    = (const float*)d_in[11];
    const float* b2_o    = (const float*)d_in[12];
    (void)in_sizes; (void)n_in; (void)out_size;

    Specs sp3, sp2;
    unsigned tot3 = compute_specs(3, &sp3);
    compute_specs(2, &sp2);

    // ws layout: [fp8 table][S 4096][partial 16][8 hash feat slabs]
    size_t tabB = (((size_t)tot3 * 2) + 255) & ~(size_t)255;
    size_t head = tabB + (size_t)B_LINES * 4 + 64;
    head = (head + 63) & ~(size_t)63;
    long max_lines = 0;
    if (ws_size > head + 64)
        max_lines = (long)((ws_size - head - 64) / ((size_t)P_PTS * 8 * 4));

    float* S       = (float*)((char*)d_ws + tabB);
    float* partial = S + B_LINES;

    if (max_lines >= 64) {
        // Phased fp8 path.
        ushort_t* tabq = (ushort_t*)d_ws;
        unsigned* featbuf = (unsigned*)((char*)d_ws + head);

        int chunk_lines = (int)(max_lines < B_LINES ? max_lines : B_LINES);
        int nch = (B_LINES + chunk_lines - 1) / chunk_lines;

        HashScales hs;
        for (int k = 0; k < 8; ++k) hs.s[k] = sp3.L[4 + k].scale;
        const unsigned hash_off0 = sp3.L[4].off;

        convert_kernel<<<((int)tot3 + 255) / 256, 256, 0, stream>>>(
            (const float2*)table_o, tabq, (int)tot3);

        for (int ch = 0; ch < nch; ++ch) {
            int line0 = ch * chunk_lines;
            int lines = B_LINES - line0 < chunk_lines ? B_LINES - line0
                                                      : chunk_lines;
            int npts = lines * P_PTS;
            int pbase = line0 * P_PTS;
            enc_hash_all_kernel<<<NBLK_PER_LEV * 8, 256, 0, stream>>>(
                pts, pbase, npts, tabq, hash_off0, hs, featbuf);
            mlp_loss_fused_kernel<<<lines, 256, 0, stream>>>(
                pts, featbuf, npts, gt, line0, tabq,
                w1_o, b1_o, w2_o, b2_o, S, sp3);
        }
    } else {
        // Fallback: monolithic f32 path (needs only S+partial in ws).
        opacity_mono_kernel<<<B_LINES, 256, 0, stream>>>(
            pts, gt, (const float2*)table_o, w1_o, b1_o, w2_o, b2_o, S, sp3);
    }

    conf_kernel<<<16, 256, 0, stream>>>(
        line, (const float2*)table_c, w1_c, b1_c, w2_c, b2_c, S, partial, sp2);
    final_kernel<<<1, 64, 0, stream>>>(partial, (float*)d_out);
}